// Round 1
// baseline (1751.341 us; speedup 1.0000x reference)
//
#include <hip/hip_runtime.h>
#include <hip/hip_bf16.h>
#include <math.h>

#define EMB  2048
#define NH   16
#define HD   128
#define SEQ  2048
#define BATCH 2
#define MTOK (BATCH*SEQ)   // 4096 tokens

using bf16x8 = __attribute__((ext_vector_type(8))) __bf16;
using f32x4  = __attribute__((ext_vector_type(4))) float;

__device__ __forceinline__ unsigned short f2bf(float x) {
    unsigned int u = __float_as_uint(x);
    u += 0x7fffu + ((u >> 16) & 1u);   // round-to-nearest-even
    return (unsigned short)(u >> 16);
}

__device__ __forceinline__ float gelu_exact(float x) {
    return 0.5f * x * (1.0f + erff(x * 0.70710678118654752f));
}

// ---------------- flat f32 -> bf16 convert (4 elems/thread) ----------------
__global__ __launch_bounds__(256) void k_conv(const float* __restrict__ in,
                                              unsigned short* __restrict__ out, int n4) {
    int i = blockIdx.x * 256 + threadIdx.x;
    if (i >= n4) return;
    float4 v = ((const float4*)in)[i];
    ushort4 o;
    o.x = f2bf(v.x); o.y = f2bf(v.y); o.z = f2bf(v.z); o.w = f2bf(v.w);
    ((ushort4*)out)[i] = o;
}

// ------------- W[K][N] f32 -> Wt[N][K] bf16 (tiled transpose) ---------------
__global__ __launch_bounds__(256) void k_transconv(const float* __restrict__ W,
                                                   unsigned short* __restrict__ Wt,
                                                   int K, int N) {
    __shared__ float t[32][33];
    int tx = threadIdx.x & 31, ty = threadIdx.x >> 5;   // 32 x 8
    int c0 = blockIdx.x * 32, r0 = blockIdx.y * 32;
    #pragma unroll
    for (int i = 0; i < 4; ++i)
        t[ty + i*8][tx] = W[(size_t)(r0 + ty + i*8) * N + c0 + tx];
    __syncthreads();
    #pragma unroll
    for (int i = 0; i < 4; ++i)
        Wt[(size_t)(c0 + ty + i*8) * K + r0 + tx] = f2bf(t[tx][ty + i*8]);
}

// ----- K[b,s,h,d] f32 -> KT[(b*NH+h)][d][s] f32 (per-head transpose) --------
__global__ __launch_bounds__(256) void k_ktrans(const float* __restrict__ Kin,
                                                float* __restrict__ KT) {
    __shared__ float t[32][33];
    int tx = threadIdx.x & 31, ty = threadIdx.x >> 5;
    int s0 = blockIdx.x * 32, d0 = blockIdx.y * 32;
    int bh = blockIdx.z; int b = bh >> 4, h = bh & 15;
    #pragma unroll
    for (int i = 0; i < 4; ++i)
        t[ty + i*8][tx] = Kin[(size_t)(b*SEQ + s0 + ty + i*8) * EMB + h*HD + d0 + tx];
    __syncthreads();
    #pragma unroll
    for (int i = 0; i < 4; ++i)
        KT[(size_t)(bh*HD + d0 + ty + i*8) * SEQ + s0 + tx] = t[tx][ty + i*8];
}

// ---------------- bf16 MFMA GEMM: C = A[M,K] @ Bt[N,K]^T + bias -------------
// EPI: 0 = f32 out; 1 = f32 out + residual; 2 = bf16 out with exact GELU
template<int EPI>
__global__ __launch_bounds__(256) void k_gemm(const unsigned short* __restrict__ A,
                                              const unsigned short* __restrict__ Bt,
                                              const float* __restrict__ bias,
                                              const float* __restrict__ res,
                                              void* __restrict__ Cout,
                                              int M, int N, int K) {
    __shared__ unsigned short As[128 * 32];
    __shared__ unsigned short Bs[128 * 32];
    const int tid = threadIdx.x;
    const int lane = tid & 63, wid = tid >> 6;
    const int wm = wid >> 1, wn = wid & 1;            // 2x2 waves, 64x64 each
    const int bm = blockIdx.x, bn = blockIdx.y;
    f32x4 acc[4][4] = {};
    const int srow = wid * 16 + (lane >> 2);          // staging row within 64-row half
    const int scol = (lane & 3) * 8;                  // staging col (8 bf16 = 16B)
    const unsigned short* Ab = A  + (size_t)bm * 128 * K;
    const unsigned short* Bb = Bt + (size_t)bn * 128 * K;

    for (int kt = 0; kt < K; kt += 32) {
        #pragma unroll
        for (int i = 0; i < 2; ++i) {
            const unsigned short* ga = Ab + (size_t)(i*64 + srow) * K + kt + scol;
            const unsigned short* gb = Bb + (size_t)(i*64 + srow) * K + kt + scol;
            __builtin_amdgcn_global_load_lds(
                (const __attribute__((address_space(1))) void*)ga,
                (__attribute__((address_space(3))) void*)&As[(i*64 + wid*16) * 32], 16, 0, 0);
            __builtin_amdgcn_global_load_lds(
                (const __attribute__((address_space(1))) void*)gb,
                (__attribute__((address_space(3))) void*)&Bs[(i*64 + wid*16) * 32], 16, 0, 0);
        }
        __syncthreads();   // compiler emits vmcnt(0) drain before barrier

        bf16x8 af[4], bfr[4];
        #pragma unroll
        for (int mi = 0; mi < 4; ++mi)
            af[mi] = *(const bf16x8*)&As[(wm*64 + mi*16 + (lane & 15)) * 32 + (lane >> 4) * 8];
        #pragma unroll
        for (int ni = 0; ni < 4; ++ni)
            bfr[ni] = *(const bf16x8*)&Bs[(wn*64 + ni*16 + (lane & 15)) * 32 + (lane >> 4) * 8];
        #pragma unroll
        for (int mi = 0; mi < 4; ++mi)
            #pragma unroll
            for (int ni = 0; ni < 4; ++ni)
                acc[mi][ni] = __builtin_amdgcn_mfma_f32_16x16x32_bf16(af[mi], bfr[ni], acc[mi][ni], 0, 0, 0);
        __syncthreads();
    }

    const int row0 = bm*128 + wm*64, col0 = bn*128 + wn*64;
    #pragma unroll
    for (int mi = 0; mi < 4; ++mi) {
        #pragma unroll
        for (int ni = 0; ni < 4; ++ni) {
            const int c = col0 + ni*16 + (lane & 15);
            const float bv = bias[c];
            #pragma unroll
            for (int j = 0; j < 4; ++j) {
                const int r = row0 + mi*16 + (lane >> 4)*4 + j;
                float v = acc[mi][ni][j] + bv;
                if (EPI == 1) v += res[(size_t)r * N + c];
                if (EPI == 2) {
                    ((unsigned short*)Cout)[(size_t)r * N + c] = f2bf(gelu_exact(v));
                } else {
                    ((float*)Cout)[(size_t)r * N + c] = v;
                }
            }
        }
    }
}

// ---------------- causal attention, fp32 vector, online softmax -------------
// grid: (SEQ/16, NH, BATCH); 4 waves/block, 4 query rows per wave
__global__ __launch_bounds__(256) void k_attn(const float* __restrict__ Q,
                                              const float* __restrict__ KT,
                                              const float* __restrict__ V,
                                              float* __restrict__ O) {
    const int lane = threadIdx.x & 63, wid = threadIdx.x >> 6;
    const int h = blockIdx.y, b = blockIdx.z;
    const int rowblk = blockIdx.x * 16;
    __shared__ float q_lds[16][128];
    __shared__ float p_lds[4][4][256];

    for (int i = threadIdx.x; i < 16 * 32; i += 256) {
        int r = i >> 5, c4 = i & 31;
        ((float4*)q_lds[r])[c4] =
            *(const float4*)(Q + (size_t)(b*SEQ + rowblk + r) * EMB + h*HD + c4*4);
    }
    __syncthreads();

    const int nch = rowblk / 256 + 1;       // uniform across block (16 | 256)
    float m[4], l[4], cacc[4][2];
    #pragma unroll
    for (int r = 0; r < 4; ++r) { m[r] = -1e30f; l[r] = 0.f; cacc[r][0] = 0.f; cacc[r][1] = 0.f; }
    const int d0 = lane * 2;
    const float* KTb = KT + (size_t)(b*NH + h) * HD * SEQ;
    const float scale = 0.08838834764831845f;   // 1/sqrt(128)

    for (int tc = 0; tc < nch * 256; tc += 256) {
        // ---- scores: lane owns keys tc + lane*4 .. +3
        float sc[4][4] = {};
        const float* kp = KTb + tc + lane * 4;
        for (int d = 0; d < 128; d += 4) {
            float4 qv[4];
            #pragma unroll
            for (int r = 0; r < 4; ++r) qv[r] = *(const float4*)&q_lds[wid*4 + r][d];
            #pragma unroll
            for (int dd = 0; dd < 4; ++dd) {
                float4 kv = *(const float4*)(kp + (size_t)(d + dd) * SEQ);
                #pragma unroll
                for (int r = 0; r < 4; ++r) {
                    const float qs = ((const float*)&qv[r])[dd];
                    sc[r][0] = fmaf(qs, kv.x, sc[r][0]);
                    sc[r][1] = fmaf(qs, kv.y, sc[r][1]);
                    sc[r][2] = fmaf(qs, kv.z, sc[r][2]);
                    sc[r][3] = fmaf(qs, kv.w, sc[r][3]);
                }
            }
        }
        // ---- online softmax (causal mask explicit, p=0 for invalid)
        #pragma unroll
        for (int r = 0; r < 4; ++r) {
            const int srowq = rowblk + wid*4 + r;
            float sv[4]; float mx = -1e30f;
            #pragma unroll
            for (int j = 0; j < 4; ++j) {
                int t = tc + lane*4 + j;
                sv[j] = (t <= srowq) ? sc[r][j] * scale : -1e30f;
                mx = fmaxf(mx, sv[j]);
            }
            #pragma unroll
            for (int o = 32; o; o >>= 1) mx = fmaxf(mx, __shfl_xor(mx, o));
            const float mn = fmaxf(m[r], mx);
            const float corr = __expf(m[r] - mn);
            float ps = 0.f; float4 pw;
            #pragma unroll
            for (int j = 0; j < 4; ++j) {
                int t = tc + lane*4 + j;
                float p = (t <= srowq) ? __expf(sv[j] - mn) : 0.f;
                ps += p;
                ((float*)&pw)[j] = p;
            }
            *(float4*)&p_lds[wid][r][lane*4] = pw;
            #pragma unroll
            for (int o = 32; o; o >>= 1) ps += __shfl_xor(ps, o);
            l[r] = l[r] * corr + ps;
            cacc[r][0] *= corr; cacc[r][1] *= corr;
            m[r] = mn;
        }
        asm volatile("s_waitcnt lgkmcnt(0)" ::: "memory");
        // ---- PV: lane owns d-pair d0, d0+1
        const float* vp = V + (size_t)(b*SEQ + tc) * EMB + h*HD + d0;
        for (int t4 = 0; t4 < 64; ++t4) {
            float4 pv[4];
            #pragma unroll
            for (int r = 0; r < 4; ++r) pv[r] = *(const float4*)&p_lds[wid][r][t4*4];
            #pragma unroll
            for (int j = 0; j < 4; ++j) {
                float2 vv = *(const float2*)(vp + (size_t)(t4*4 + j) * EMB);
                #pragma unroll
                for (int r = 0; r < 4; ++r) {
                    const float p = ((const float*)&pv[r])[j];
                    cacc[r][0] = fmaf(p, vv.x, cacc[r][0]);
                    cacc[r][1] = fmaf(p, vv.y, cacc[r][1]);
                }
            }
        }
    }
    #pragma unroll
    for (int r = 0; r < 4; ++r) {
        const float inv = 1.0f / l[r];
        float2 o2; o2.x = cacc[r][0] * inv; o2.y = cacc[r][1] * inv;
        *(float2*)(O + (size_t)(b*SEQ + rowblk + wid*4 + r) * EMB + h*HD + d0) = o2;
    }
}

// ---------------- row LayerNorm over 2048, optional bf16 copy ---------------
__global__ __launch_bounds__(256) void k_ln(const float* __restrict__ X,
                                            const float* __restrict__ g,
                                            const float* __restrict__ be,
                                            float* __restrict__ Of32,
                                            unsigned short* __restrict__ Obf16) {
    const int row = blockIdx.x;
    const float* x = X + (size_t)row * EMB;
    float4 v[2];
    float s = 0.f, ss = 0.f;
    #pragma unroll
    for (int i = 0; i < 2; ++i) {
        v[i] = ((const float4*)x)[threadIdx.x + i*256];
        s  += v[i].x + v[i].y + v[i].z + v[i].w;
        ss += v[i].x*v[i].x + v[i].y*v[i].y + v[i].z*v[i].z + v[i].w*v[i].w;
    }
    #pragma unroll
    for (int o = 32; o; o >>= 1) { s += __shfl_xor(s, o); ss += __shfl_xor(ss, o); }
    __shared__ float red[2][4];
    const int lane = threadIdx.x & 63, wid = threadIdx.x >> 6;
    if (lane == 0) { red[0][wid] = s; red[1][wid] = ss; }
    __syncthreads();
    s  = red[0][0] + red[0][1] + red[0][2] + red[0][3];
    ss = red[1][0] + red[1][1] + red[1][2] + red[1][3];
    const float mu = s * (1.0f / EMB);
    const float var = ss * (1.0f / EMB) - mu * mu;
    const float rs = rsqrtf(var + 1e-5f);
    #pragma unroll
    for (int i = 0; i < 2; ++i) {
        const int c4 = threadIdx.x + i*256;
        float4 gv = ((const float4*)g)[c4];
        float4 bv = ((const float4*)be)[c4];
        float4 y;
        y.x = (v[i].x - mu) * rs * gv.x + bv.x;
        y.y = (v[i].y - mu) * rs * gv.y + bv.y;
        y.z = (v[i].z - mu) * rs * gv.z + bv.z;
        y.w = (v[i].w - mu) * rs * gv.w + bv.w;
        if (Of32)  ((float4*)(Of32 + (size_t)row * EMB))[c4] = y;
        if (Obf16) {
            ushort4 u; u.x = f2bf(y.x); u.y = f2bf(y.y); u.z = f2bf(y.z); u.w = f2bf(y.w);
            ((ushort4*)(Obf16 + (size_t)row * EMB))[c4] = u;
        }
    }
}

extern "C" void kernel_launch(void* const* d_in, const int* in_sizes, int n_in,
                              void* d_out, int out_size, void* d_ws, size_t ws_size,
                              hipStream_t stream) {
    const float* emb = (const float*)d_in[0];
    const float* Wq  = (const float*)d_in[1];  const float* bq  = (const float*)d_in[2];
    const float* Wk  = (const float*)d_in[3];  const float* bk  = (const float*)d_in[4];
    const float* Wv  = (const float*)d_in[5];  const float* bv  = (const float*)d_in[6];
    const float* Wfc = (const float*)d_in[7];  const float* bfc = (const float*)d_in[8];
    const float* g1  = (const float*)d_in[9];  const float* be1 = (const float*)d_in[10];
    const float* W1  = (const float*)d_in[11]; const float* b1  = (const float*)d_in[12];
    const float* W2  = (const float*)d_in[13]; const float* b2  = (const float*)d_in[14];
    const float* g2  = (const float*)d_in[15]; const float* be2 = (const float*)d_in[16];

    // workspace layout (256 MB total), lifetime-based reuse:
    char* ws = (char*)d_ws;
    unsigned short* aB   = (unsigned short*)(ws + (size_t)(0   ) * (1u<<20)); // 16MB: emb_bf16 -> ctx_bf16
    unsigned short* ln1B = (unsigned short*)(ws + (size_t)(16  ) * (1u<<20)); // 16MB: ln1 bf16
    unsigned short* WtB  = (unsigned short*)(ws + (size_t)(32  ) * (1u<<20)); // 32MB: transposed weight (serial reuse)
    float*          Qf   = (float*)         (ws + (size_t)(64  ) * (1u<<20)); // 32MB: Q -> x1
    float*          Kf   = (float*)         (ws + (size_t)(96  ) * (1u<<20)); // 32MB: K -> ctx
    float*          Vf   = (float*)         (ws + (size_t)(128 ) * (1u<<20)); // 32MB: V -> ln1 f32
    float*          KTf  = (float*)         (ws + (size_t)(160 ) * (1u<<20)); // 32MB: K^T
    unsigned short* hB   = (unsigned short*)(ws + (size_t)(192 ) * (1u<<20)); // 64MB: GELU(ffn1) bf16

    const dim3 blk(256);
    const int n4 = MTOK * EMB / 4;

    // embeddings -> bf16
    k_conv<<<dim3(n4 / 256), blk, 0, stream>>>(emb, aB, n4);

    // Q, K, V projections
    k_transconv<<<dim3(EMB/32, EMB/32), blk, 0, stream>>>(Wq, WtB, EMB, EMB);
    k_gemm<0><<<dim3(MTOK/128, EMB/128), blk, 0, stream>>>(aB, WtB, bq, nullptr, Qf, MTOK, EMB, EMB);
    k_transconv<<<dim3(EMB/32, EMB/32), blk, 0, stream>>>(Wk, WtB, EMB, EMB);
    k_gemm<0><<<dim3(MTOK/128, EMB/128), blk, 0, stream>>>(aB, WtB, bk, nullptr, Kf, MTOK, EMB, EMB);
    k_transconv<<<dim3(EMB/32, EMB/32), blk, 0, stream>>>(Wv, WtB, EMB, EMB);
    k_gemm<0><<<dim3(MTOK/128, EMB/128), blk, 0, stream>>>(aB, WtB, bv, nullptr, Vf, MTOK, EMB, EMB);

    // K transpose per head, then attention (ctx overwrites K region)
    k_ktrans<<<dim3(SEQ/32, HD/32, BATCH*NH), blk, 0, stream>>>(Kf, KTf);
    k_attn<<<dim3(SEQ/16, NH, BATCH), blk, 0, stream>>>(Qf, KTf, Vf, Kf);

    // ctx -> bf16 (reuse aB), x1 = ctx@Wfc + bfc + emb -> Qf
    k_conv<<<dim3(n4 / 256), blk, 0, stream>>>(Kf, aB, n4);
    k_transconv<<<dim3(EMB/32, EMB/32), blk, 0, stream>>>(Wfc, WtB, EMB, EMB);
    k_gemm<1><<<dim3(MTOK/128, EMB/128), blk, 0, stream>>>(aB, WtB, bfc, emb, Qf, MTOK, EMB, EMB);

    // LN1 -> f32 (Vf) + bf16 (ln1B)
    k_ln<<<dim3(MTOK), blk, 0, stream>>>(Qf, g1, be1, Vf, ln1B);

    // h = gelu(ln1 @ W1 + b1) -> bf16
    k_transconv<<<dim3(4*EMB/32, EMB/32), blk, 0, stream>>>(W1, WtB, EMB, 4*EMB);
    k_gemm<2><<<dim3(MTOK/128, (4*EMB)/128), blk, 0, stream>>>(ln1B, WtB, b1, nullptr, hB, MTOK, 4*EMB, EMB);

    // x2 = h @ W2 + b2 + ln1 -> d_out
    k_transconv<<<dim3(EMB/32, (4*EMB)/32), blk, 0, stream>>>(W2, WtB, 4*EMB, EMB);
    k_gemm<1><<<dim3(MTOK/128, EMB/128), blk, 0, stream>>>(hB, WtB, b2, Vf, (float*)d_out, MTOK, EMB, 4*EMB);

    // LN2 in-place on d_out
    k_ln<<<dim3(MTOK), blk, 0, stream>>>((const float*)d_out, g2, be2, (float*)d_out, nullptr);
}

// Round 2
// 1257.009 us; speedup vs baseline: 1.3933x; 1.3933x over previous
//
#include <hip/hip_runtime.h>
#include <hip/hip_bf16.h>
#include <math.h>

#define EMB  2048
#define NH   16
#define HD   128
#define SEQ  2048
#define BATCH 2
#define MTOK (BATCH*SEQ)   // 4096 tokens

using bf16x8 = __attribute__((ext_vector_type(8))) __bf16;
using f32x4  = __attribute__((ext_vector_type(4))) float;

__device__ __forceinline__ unsigned short f2bf(float x) {
    unsigned int u = __float_as_uint(x);
    u += 0x7fffu + ((u >> 16) & 1u);   // round-to-nearest-even
    return (unsigned short)(u >> 16);
}

__device__ __forceinline__ float gelu_exact(float x) {
    return 0.5f * x * (1.0f + erff(x * 0.70710678118654752f));
}

// ---------------- flat f32 -> bf16 convert (4 elems/thread) ----------------
__global__ __launch_bounds__(256) void k_conv(const float* __restrict__ in,
                                              unsigned short* __restrict__ out, int n4) {
    int i = blockIdx.x * 256 + threadIdx.x;
    if (i >= n4) return;
    float4 v = ((const float4*)in)[i];
    ushort4 o;
    o.x = f2bf(v.x); o.y = f2bf(v.y); o.z = f2bf(v.z); o.w = f2bf(v.w);
    ((ushort4*)out)[i] = o;
}

// ------------- W[K][N] f32 -> Wt[N][K] bf16 (tiled transpose) ---------------
__global__ __launch_bounds__(256) void k_transconv(const float* __restrict__ W,
                                                   unsigned short* __restrict__ Wt,
                                                   int K, int N) {
    __shared__ float t[32][33];
    int tx = threadIdx.x & 31, ty = threadIdx.x >> 5;   // 32 x 8
    int c0 = blockIdx.x * 32, r0 = blockIdx.y * 32;
    #pragma unroll
    for (int i = 0; i < 4; ++i)
        t[ty + i*8][tx] = W[(size_t)(r0 + ty + i*8) * N + c0 + tx];
    __syncthreads();
    #pragma unroll
    for (int i = 0; i < 4; ++i)
        Wt[(size_t)(c0 + ty + i*8) * K + r0 + tx] = f2bf(t[tx][ty + i*8]);
}

// ---------------- bf16 MFMA GEMM: C = A[M,K] @ Bt[N,K]^T + bias -------------
// EPI: 0=f32 out; 1=f32 out + residual; 2=bf16 GELU out; 3=bf16 out;
//      4=bf16 out transposed per-head -> VT[(b*NH+h)*HD + d][SEQ]
template<int EPI>
__global__ __launch_bounds__(256) void k_gemm(const unsigned short* __restrict__ A,
                                              const unsigned short* __restrict__ Bt,
                                              const float* __restrict__ bias,
                                              const float* __restrict__ res,
                                              void* __restrict__ Cout,
                                              int M, int N, int K) {
    __shared__ unsigned short As[128 * 32];
    __shared__ unsigned short Bs[128 * 32];
    const int tid = threadIdx.x;
    const int lane = tid & 63, wid = tid >> 6;
    const int wm = wid >> 1, wn = wid & 1;            // 2x2 waves, 64x64 each
    const int bm = blockIdx.x, bn = blockIdx.y;
    f32x4 acc[4][4] = {};
    const int srow = wid * 16 + (lane >> 2);          // staging row within 64-row half
    const int scol = (lane & 3) * 8;                  // staging col (8 bf16 = 16B)
    const unsigned short* Ab = A  + (size_t)bm * 128 * K;
    const unsigned short* Bb = Bt + (size_t)bn * 128 * K;

    for (int kt = 0; kt < K; kt += 32) {
        #pragma unroll
        for (int i = 0; i < 2; ++i) {
            const unsigned short* ga = Ab + (size_t)(i*64 + srow) * K + kt + scol;
            const unsigned short* gb = Bb + (size_t)(i*64 + srow) * K + kt + scol;
            __builtin_amdgcn_global_load_lds(
                (const __attribute__((address_space(1))) void*)ga,
                (__attribute__((address_space(3))) void*)&As[(i*64 + wid*16) * 32], 16, 0, 0);
            __builtin_amdgcn_global_load_lds(
                (const __attribute__((address_space(1))) void*)gb,
                (__attribute__((address_space(3))) void*)&Bs[(i*64 + wid*16) * 32], 16, 0, 0);
        }
        __syncthreads();

        bf16x8 af[4], bfr[4];
        #pragma unroll
        for (int mi = 0; mi < 4; ++mi)
            af[mi] = *(const bf16x8*)&As[(wm*64 + mi*16 + (lane & 15)) * 32 + (lane >> 4) * 8];
        #pragma unroll
        for (int ni = 0; ni < 4; ++ni)
            bfr[ni] = *(const bf16x8*)&Bs[(wn*64 + ni*16 + (lane & 15)) * 32 + (lane >> 4) * 8];
        #pragma unroll
        for (int mi = 0; mi < 4; ++mi)
            #pragma unroll
            for (int ni = 0; ni < 4; ++ni)
                acc[mi][ni] = __builtin_amdgcn_mfma_f32_16x16x32_bf16(af[mi], bfr[ni], acc[mi][ni], 0, 0, 0);
        __syncthreads();
    }

    const int row0 = bm*128 + wm*64, col0 = bn*128 + wn*64;
    #pragma unroll
    for (int mi = 0; mi < 4; ++mi) {
        #pragma unroll
        for (int ni = 0; ni < 4; ++ni) {
            const int c = col0 + ni*16 + (lane & 15);
            const int r0 = row0 + mi*16 + (lane >> 4)*4;
            const float bv = bias[c];
            float v[4];
            #pragma unroll
            for (int j = 0; j < 4; ++j) v[j] = acc[mi][ni][j] + bv;
            if (EPI == 0) {
                #pragma unroll
                for (int j = 0; j < 4; ++j) ((float*)Cout)[(size_t)(r0+j) * N + c] = v[j];
            } else if (EPI == 1) {
                #pragma unroll
                for (int j = 0; j < 4; ++j)
                    ((float*)Cout)[(size_t)(r0+j) * N + c] = v[j] + res[(size_t)(r0+j) * N + c];
            } else if (EPI == 2) {
                #pragma unroll
                for (int j = 0; j < 4; ++j)
                    ((unsigned short*)Cout)[(size_t)(r0+j) * N + c] = f2bf(gelu_exact(v[j]));
            } else if (EPI == 3) {
                #pragma unroll
                for (int j = 0; j < 4; ++j)
                    ((unsigned short*)Cout)[(size_t)(r0+j) * N + c] = f2bf(v[j]);
            } else {  // EPI == 4: per-head transposed bf16 (V -> VT[bh*HD+d][SEQ])
                const int hh = c >> 7, dd = c & 127;
                const int bb = r0 >> 11, s0 = r0 & 2047;
                ushort4 u;
                u.x = f2bf(v[0]); u.y = f2bf(v[1]); u.z = f2bf(v[2]); u.w = f2bf(v[3]);
                *(ushort4*)((unsigned short*)Cout +
                            ((size_t)((bb*NH + hh)*HD + dd) * SEQ + s0)) = u;
            }
        }
    }
}

// ---------------- MFMA flash attention (bf16, causal) -----------------------
// grid: (SEQ/64, NH, BATCH), 256 threads; wave w owns q rows blk*64+w*16..+15
// Qb,Kb: [b*SEQ+s][EMB] bf16 ; VTb: [(b*NH+h)*HD+d][SEQ] bf16 ; Ob bf16 ctx
__global__ __launch_bounds__(256) void k_attn_mfma(const unsigned short* __restrict__ Qb,
                                                   const unsigned short* __restrict__ Kb,
                                                   const unsigned short* __restrict__ VTb,
                                                   unsigned short* __restrict__ Ob) {
    const int lane = threadIdx.x & 63, w = threadIdx.x >> 6;
    const int g = lane >> 4, c = lane & 15;
    const int h = blockIdx.y, b = blockIdx.z;
    const int qb = blockIdx.x * 64 + w * 16;
    __shared__ unsigned short p_lds[4][16 * 64];     // per-wave P tile, XOR-swizzled

    // Q fragments: lane holds q row (qb+c), d = dch*32 + g*8 .. +7
    bf16x8 qf[4];
    {
        const unsigned short* qrow = Qb + (size_t)(b*SEQ + qb + c) * EMB + h*HD;
        #pragma unroll
        for (int dch = 0; dch < 4; ++dch)
            qf[dch] = *(const bf16x8*)(qrow + dch*32 + g*8);
    }

    f32x4 o[8];
    #pragma unroll
    for (int ni = 0; ni < 8; ++ni) o[ni] = (f32x4){0.f, 0.f, 0.f, 0.f};
    float m4[4], l4[4];
    #pragma unroll
    for (int j = 0; j < 4; ++j) { m4[j] = -1e30f; l4[j] = 0.f; }

    const int qmaxw = qb + 15;                       // wave-uniform causal bound
    const unsigned short* Kbase = Kb  + (size_t)(b*SEQ) * EMB + h*HD;
    const unsigned short* Vbase = VTb + (size_t)((b*NH + h) * HD) * SEQ;
    const float scale = 0.08838834764831845f;        // 1/sqrt(128)
    char* pw = (char*)&p_lds[w][0];

    const int nkv = blockIdx.x + 1;
    for (int tc = 0; tc < nkv * 64; tc += 64) {
        // ---- QK^T: 4 key sub-tiles of 16, accumulate over d (4 mfma each)
        f32x4 sc[4];
        #pragma unroll
        for (int kt = 0; kt < 4; ++kt) {
            sc[kt] = (f32x4){0.f, 0.f, 0.f, 0.f};
            if (tc + kt*16 <= qmaxw) {               // wave-uniform skip
                const unsigned short* krow = Kbase + (size_t)(tc + kt*16 + c) * EMB;
                #pragma unroll
                for (int dch = 0; dch < 4; ++dch) {
                    bf16x8 kf = *(const bf16x8*)(krow + dch*32 + g*8);
                    sc[kt] = __builtin_amdgcn_mfma_f32_16x16x32_bf16(qf[dch], kf, sc[kt], 0, 0, 0);
                }
            }
        }
        // ---- online softmax; C layout: key col = c, q row = g*4+j
        #pragma unroll
        for (int j = 0; j < 4; ++j) {
            const int q = qb + g*4 + j;
            const int row = g*4 + j;
            float sv[4]; float mx = -1e30f;
            #pragma unroll
            for (int kt = 0; kt < 4; ++kt) {
                const int key = tc + kt*16 + c;
                sv[kt] = (key <= q) ? sc[kt][j] * scale : -1e30f;
                mx = fmaxf(mx, sv[kt]);
            }
            #pragma unroll
            for (int off = 8; off; off >>= 1) mx = fmaxf(mx, __shfl_xor(mx, off));
            const float mn = fmaxf(m4[j], mx);
            const float corr = __expf(m4[j] - mn);
            float ps = 0.f;
            #pragma unroll
            for (int kt = 0; kt < 4; ++kt) {
                const float p = __expf(sv[kt] - mn);     // masked -> 0
                ps += p;
                const int byte = (row*128 + (kt*16 + c)*2) ^ ((row & 7) << 4);
                *(unsigned short*)(pw + byte) = f2bf(p);
            }
            #pragma unroll
            for (int off = 8; off; off >>= 1) ps += __shfl_xor(ps, off);
            l4[j] = l4[j] * corr + ps;
            m4[j] = mn;
            #pragma unroll
            for (int ni = 0; ni < 8; ++ni) o[ni][j] *= corr;
        }
        asm volatile("s_waitcnt lgkmcnt(0)" ::: "memory");
        __builtin_amdgcn_sched_barrier(0);
        // ---- PV: A = P (rows q=c, t contiguous from swizzled LDS), B = VT
        #pragma unroll
        for (int kc = 0; kc < 2; ++kc) {
            if (tc + kc*32 <= qmaxw) {               // wave-uniform
                const int byte = (c*128 + kc*64 + g*16) ^ ((c & 7) << 4);
                bf16x8 pa = *(const bf16x8*)(pw + byte);
                #pragma unroll
                for (int ni = 0; ni < 8; ++ni) {
                    bf16x8 vf = *(const bf16x8*)(Vbase + (size_t)(ni*16 + c) * SEQ + tc + kc*32 + g*8);
                    o[ni] = __builtin_amdgcn_mfma_f32_16x16x32_bf16(pa, vf, o[ni], 0, 0, 0);
                }
            }
        }
    }

    // ---- epilogue: normalize, write bf16 ctx
    unsigned short* orow = Ob + (size_t)(b*SEQ + qb) * EMB + h*HD;
    float inv[4];
    #pragma unroll
    for (int j = 0; j < 4; ++j) inv[j] = 1.0f / l4[j];
    #pragma unroll
    for (int ni = 0; ni < 8; ++ni)
        #pragma unroll
        for (int j = 0; j < 4; ++j)
            orow[(size_t)(g*4 + j) * EMB + ni*16 + c] = f2bf(o[ni][j] * inv[j]);
}

// ---------------- row LayerNorm over 2048, optional bf16 copy ---------------
__global__ __launch_bounds__(256) void k_ln(const float* __restrict__ X,
                                            const float* __restrict__ g,
                                            const float* __restrict__ be,
                                            float* __restrict__ Of32,
                                            unsigned short* __restrict__ Obf16) {
    const int row = blockIdx.x;
    const float* x = X + (size_t)row * EMB;
    float4 v[2];
    float s = 0.f, ss = 0.f;
    #pragma unroll
    for (int i = 0; i < 2; ++i) {
        v[i] = ((const float4*)x)[threadIdx.x + i*256];
        s  += v[i].x + v[i].y + v[i].z + v[i].w;
        ss += v[i].x*v[i].x + v[i].y*v[i].y + v[i].z*v[i].z + v[i].w*v[i].w;
    }
    #pragma unroll
    for (int o = 32; o; o >>= 1) { s += __shfl_xor(s, o); ss += __shfl_xor(ss, o); }
    __shared__ float red[2][4];
    const int lane = threadIdx.x & 63, wid = threadIdx.x >> 6;
    if (lane == 0) { red[0][wid] = s; red[1][wid] = ss; }
    __syncthreads();
    s  = red[0][0] + red[0][1] + red[0][2] + red[0][3];
    ss = red[1][0] + red[1][1] + red[1][2] + red[1][3];
    const float mu = s * (1.0f / EMB);
    const float var = ss * (1.0f / EMB) - mu * mu;
    const float rs = rsqrtf(var + 1e-5f);
    #pragma unroll
    for (int i = 0; i < 2; ++i) {
        const int c4 = threadIdx.x + i*256;
        float4 gv = ((const float4*)g)[c4];
        float4 bv = ((const float4*)be)[c4];
        float4 y;
        y.x = (v[i].x - mu) * rs * gv.x + bv.x;
        y.y = (v[i].y - mu) * rs * gv.y + bv.y;
        y.z = (v[i].z - mu) * rs * gv.z + bv.z;
        y.w = (v[i].w - mu) * rs * gv.w + bv.w;
        if (Of32)  ((float4*)(Of32 + (size_t)row * EMB))[c4] = y;
        if (Obf16) {
            ushort4 u; u.x = f2bf(y.x); u.y = f2bf(y.y); u.z = f2bf(y.z); u.w = f2bf(y.w);
            ((ushort4*)(Obf16 + (size_t)row * EMB))[c4] = u;
        }
    }
}

extern "C" void kernel_launch(void* const* d_in, const int* in_sizes, int n_in,
                              void* d_out, int out_size, void* d_ws, size_t ws_size,
                              hipStream_t stream) {
    const float* emb = (const float*)d_in[0];
    const float* Wq  = (const float*)d_in[1];  const float* bq  = (const float*)d_in[2];
    const float* Wk  = (const float*)d_in[3];  const float* bk  = (const float*)d_in[4];
    const float* Wv  = (const float*)d_in[5];  const float* bv  = (const float*)d_in[6];
    const float* Wfc = (const float*)d_in[7];  const float* bfc = (const float*)d_in[8];
    const float* g1  = (const float*)d_in[9];  const float* be1 = (const float*)d_in[10];
    const float* W1  = (const float*)d_in[11]; const float* b1  = (const float*)d_in[12];
    const float* W2  = (const float*)d_in[13]; const float* b2  = (const float*)d_in[14];
    const float* g2  = (const float*)d_in[15]; const float* be2 = (const float*)d_in[16];

    // workspace layout (240 MB used), lifetime-based reuse:
    char* ws = (char*)d_ws;
    unsigned short* aB   = (unsigned short*)(ws + (size_t)(0  ) * (1u<<20)); // 16MB: emb bf16 -> ctx bf16
    unsigned short* ln1B = (unsigned short*)(ws + (size_t)(16 ) * (1u<<20)); // 16MB
    unsigned short* WtB  = (unsigned short*)(ws + (size_t)(32 ) * (1u<<20)); // 32MB transposed weight (serial reuse)
    unsigned short* Qb   = (unsigned short*)(ws + (size_t)(64 ) * (1u<<20)); // 16MB Q bf16
    unsigned short* Kb   = (unsigned short*)(ws + (size_t)(80 ) * (1u<<20)); // 16MB K bf16
    unsigned short* VTb  = (unsigned short*)(ws + (size_t)(96 ) * (1u<<20)); // 16MB V^T bf16 per head
    float*          x1f  = (float*)         (ws + (size_t)(112) * (1u<<20)); // 32MB x1 f32
    float*          ln1f = (float*)         (ws + (size_t)(144) * (1u<<20)); // 32MB ln1 f32
    unsigned short* hB   = (unsigned short*)(ws + (size_t)(176) * (1u<<20)); // 64MB GELU(ffn1) bf16

    const dim3 blk(256);
    const int n4 = MTOK * EMB / 4;

    // embeddings -> bf16
    k_conv<<<dim3(n4 / 256), blk, 0, stream>>>(emb, aB, n4);

    // Q, K projections (bf16 out), V projection (per-head transposed bf16 out)
    k_transconv<<<dim3(EMB/32, EMB/32), blk, 0, stream>>>(Wq, WtB, EMB, EMB);
    k_gemm<3><<<dim3(MTOK/128, EMB/128), blk, 0, stream>>>(aB, WtB, bq, nullptr, Qb, MTOK, EMB, EMB);
    k_transconv<<<dim3(EMB/32, EMB/32), blk, 0, stream>>>(Wk, WtB, EMB, EMB);
    k_gemm<3><<<dim3(MTOK/128, EMB/128), blk, 0, stream>>>(aB, WtB, bk, nullptr, Kb, MTOK, EMB, EMB);
    k_transconv<<<dim3(EMB/32, EMB/32), blk, 0, stream>>>(Wv, WtB, EMB, EMB);
    k_gemm<4><<<dim3(MTOK/128, EMB/128), blk, 0, stream>>>(aB, WtB, bv, nullptr, VTb, MTOK, EMB, EMB);

    // MFMA flash attention -> ctx bf16 (overwrites aB)
    k_attn_mfma<<<dim3(SEQ/64, NH, BATCH), blk, 0, stream>>>(Qb, Kb, VTb, aB);

    // x1 = ctx@Wfc + bfc + emb -> x1f
    k_transconv<<<dim3(EMB/32, EMB/32), blk, 0, stream>>>(Wfc, WtB, EMB, EMB);
    k_gemm<1><<<dim3(MTOK/128, EMB/128), blk, 0, stream>>>(aB, WtB, bfc, emb, x1f, MTOK, EMB, EMB);

    // LN1 -> f32 (ln1f) + bf16 (ln1B)
    k_ln<<<dim3(MTOK), blk, 0, stream>>>(x1f, g1, be1, ln1f, ln1B);

    // h = gelu(ln1 @ W1 + b1) -> bf16
    k_transconv<<<dim3(4*EMB/32, EMB/32), blk, 0, stream>>>(W1, WtB, EMB, 4*EMB);
    k_gemm<2><<<dim3(MTOK/128, (4*EMB)/128), blk, 0, stream>>>(ln1B, WtB, b1, nullptr, hB, MTOK, 4*EMB, EMB);

    // x2 = h @ W2 + b2 + ln1 -> d_out
    k_transconv<<<dim3(EMB/32, (4*EMB)/32), blk, 0, stream>>>(W2, WtB, 4*EMB, EMB);
    k_gemm<1><<<dim3(MTOK/128, EMB/128), blk, 0, stream>>>(hB, WtB, b2, ln1f, (float*)d_out, MTOK, EMB, 4*EMB);

    // LN2 in-place on d_out
    k_ln<<<dim3(MTOK), blk, 0, stream>>>((const float*)d_out, g2, be2, (float*)d_out, nullptr);
}

// Round 3
// 1078.139 us; speedup vs baseline: 1.6244x; 1.1659x over previous
//
#include <hip/hip_runtime.h>
#include <hip/hip_bf16.h>
#include <math.h>

#define EMB  2048
#define NH   16
#define HD   128
#define SEQ  2048
#define BATCH 2
#define MTOK (BATCH*SEQ)   // 4096 tokens

using bf16x8 = __attribute__((ext_vector_type(8))) __bf16;
using f32x4  = __attribute__((ext_vector_type(4))) float;

__device__ __forceinline__ unsigned short f2bf(float x) {
    unsigned int u = __float_as_uint(x);
    u += 0x7fffu + ((u >> 16) & 1u);   // round-to-nearest-even
    return (unsigned short)(u >> 16);
}

__device__ __forceinline__ float gelu_exact(float x) {
    return 0.5f * x * (1.0f + erff(x * 0.70710678118654752f));
}

// ---------------- flat f32 -> bf16 convert (4 elems/thread) ----------------
__global__ __launch_bounds__(256) void k_conv(const float* __restrict__ in,
                                              unsigned short* __restrict__ out, int n4) {
    int i = blockIdx.x * 256 + threadIdx.x;
    if (i >= n4) return;
    float4 v = ((const float4*)in)[i];
    ushort4 o;
    o.x = f2bf(v.x); o.y = f2bf(v.y); o.z = f2bf(v.z); o.w = f2bf(v.w);
    ((ushort4*)out)[i] = o;
}

// ------------- W[K][N] f32 -> Wt[N][K] bf16 (tiled transpose) ---------------
__global__ __launch_bounds__(256) void k_transconv(const float* __restrict__ W,
                                                   unsigned short* __restrict__ Wt,
                                                   int K, int N) {
    __shared__ float t[32][33];
    int tx = threadIdx.x & 31, ty = threadIdx.x >> 5;   // 32 x 8
    int c0 = blockIdx.x * 32, r0 = blockIdx.y * 32;
    #pragma unroll
    for (int i = 0; i < 4; ++i)
        t[ty + i*8][tx] = W[(size_t)(r0 + ty + i*8) * N + c0 + tx];
    __syncthreads();
    #pragma unroll
    for (int i = 0; i < 4; ++i)
        Wt[(size_t)(c0 + ty + i*8) * K + r0 + tx] = f2bf(t[tx][ty + i*8]);
}

// ---------------- bf16 MFMA GEMM: C = A[M,K] @ Bt[N,K]^T + bias -------------
// EPI: 0=f32 out; 1=f32 out + residual; 2=bf16 GELU out; 3=bf16 out;
//      4=bf16 out transposed per-head -> VT[(b*NH+h)*HD + d][SEQ]
template<int EPI>
__global__ __launch_bounds__(256) void k_gemm(const unsigned short* __restrict__ A,
                                              const unsigned short* __restrict__ Bt,
                                              const float* __restrict__ bias,
                                              const float* __restrict__ res,
                                              void* __restrict__ Cout,
                                              int M, int N, int K) {
    __shared__ unsigned short As[128 * 32];
    __shared__ unsigned short Bs[128 * 32];
    const int tid = threadIdx.x;
    const int lane = tid & 63, wid = tid >> 6;
    const int wm = wid >> 1, wn = wid & 1;            // 2x2 waves, 64x64 each
    const int bm = blockIdx.x, bn = blockIdx.y;
    f32x4 acc[4][4] = {};
    const int srow = wid * 16 + (lane >> 2);          // staging row within 64-row half
    const int scol = (lane & 3) * 8;                  // staging col (8 bf16 = 16B)
    const unsigned short* Ab = A  + (size_t)bm * 128 * K;
    const unsigned short* Bb = Bt + (size_t)bn * 128 * K;

    for (int kt = 0; kt < K; kt += 32) {
        #pragma unroll
        for (int i = 0; i < 2; ++i) {
            const unsigned short* ga = Ab + (size_t)(i*64 + srow) * K + kt + scol;
            const unsigned short* gb = Bb + (size_t)(i*64 + srow) * K + kt + scol;
            __builtin_amdgcn_global_load_lds(
                (const __attribute__((address_space(1))) void*)ga,
                (__attribute__((address_space(3))) void*)&As[(i*64 + wid*16) * 32], 16, 0, 0);
            __builtin_amdgcn_global_load_lds(
                (const __attribute__((address_space(1))) void*)gb,
                (__attribute__((address_space(3))) void*)&Bs[(i*64 + wid*16) * 32], 16, 0, 0);
        }
        __syncthreads();

        bf16x8 af[4], bfr[4];
        #pragma unroll
        for (int mi = 0; mi < 4; ++mi)
            af[mi] = *(const bf16x8*)&As[(wm*64 + mi*16 + (lane & 15)) * 32 + (lane >> 4) * 8];
        #pragma unroll
        for (int ni = 0; ni < 4; ++ni)
            bfr[ni] = *(const bf16x8*)&Bs[(wn*64 + ni*16 + (lane & 15)) * 32 + (lane >> 4) * 8];
        #pragma unroll
        for (int mi = 0; mi < 4; ++mi)
            #pragma unroll
            for (int ni = 0; ni < 4; ++ni)
                acc[mi][ni] = __builtin_amdgcn_mfma_f32_16x16x32_bf16(af[mi], bfr[ni], acc[mi][ni], 0, 0, 0);
        __syncthreads();
    }

    const int row0 = bm*128 + wm*64, col0 = bn*128 + wn*64;
    #pragma unroll
    for (int mi = 0; mi < 4; ++mi) {
        #pragma unroll
        for (int ni = 0; ni < 4; ++ni) {
            const int c = col0 + ni*16 + (lane & 15);
            const int r0 = row0 + mi*16 + (lane >> 4)*4;
            const float bv = bias[c];
            float v[4];
            #pragma unroll
            for (int j = 0; j < 4; ++j) v[j] = acc[mi][ni][j] + bv;
            if (EPI == 0) {
                #pragma unroll
                for (int j = 0; j < 4; ++j) ((float*)Cout)[(size_t)(r0+j) * N + c] = v[j];
            } else if (EPI == 1) {
                #pragma unroll
                for (int j = 0; j < 4; ++j)
                    ((float*)Cout)[(size_t)(r0+j) * N + c] = v[j] + res[(size_t)(r0+j) * N + c];
            } else if (EPI == 2) {
                #pragma unroll
                for (int j = 0; j < 4; ++j)
                    ((unsigned short*)Cout)[(size_t)(r0+j) * N + c] = f2bf(gelu_exact(v[j]));
            } else if (EPI == 3) {
                #pragma unroll
                for (int j = 0; j < 4; ++j)
                    ((unsigned short*)Cout)[(size_t)(r0+j) * N + c] = f2bf(v[j]);
            } else {  // EPI == 4: per-head transposed bf16 (V -> VT[bh*HD+d][SEQ])
                const int hh = c >> 7, dd = c & 127;
                const int bb = r0 >> 11, s0 = r0 & 2047;
                ushort4 u;
                u.x = f2bf(v[0]); u.y = f2bf(v[1]); u.z = f2bf(v[2]); u.w = f2bf(v[3]);
                *(ushort4*)((unsigned short*)Cout +
                            ((size_t)((bb*NH + hh)*HD + dd) * SEQ + s0)) = u;
            }
        }
    }
}

// ------------- MFMA flash attention, KV-split partials (bf16, causal) -------
// CHUNK = 512 keys (8 tiles of 64). Per (b,h): 80 blocks over (qt, ks):
//   qt = 8a+r, nks(qt) = a+1, slot offset(qt) = (a+1)*(4a+r).
// Each block: 4 waves, wave w owns q rows qt*64+w*16 .. +15; writes
// unnormalized partial o[64][128] f32 + m,l per row.
__global__ __launch_bounds__(256) void k_attn_part(const unsigned short* __restrict__ Qb,
                                                   const unsigned short* __restrict__ Kb,
                                                   const unsigned short* __restrict__ VTb,
                                                   float* __restrict__ Opart,
                                                   float* __restrict__ Ml) {
    const int lane = threadIdx.x & 63, w = threadIdx.x >> 6;
    const int g = lane >> 4, c = lane & 15;
    const int h = blockIdx.y, b = blockIdx.z;
    // decode blockIdx.x in [0,80) -> (qt, ks); group a boundaries 0,8,24,48,80
    const int i = blockIdx.x;
    int a = 0;
    while (4 * (a + 1) * (a + 2) <= i) ++a;
    const int j0 = i - 4 * a * (a + 1);
    const int qt = 8 * a + j0 / (a + 1);
    const int ks = j0 % (a + 1);
    const int qb = qt * 64 + w * 16;
    const int tc0 = ks * 512;
    __shared__ unsigned short p_lds[4][16 * 64];     // per-wave P tile, XOR-swizzled

    // Q fragments: lane holds q row (qb+c), d = dch*32 + g*8 .. +7
    bf16x8 qf[4];
    {
        const unsigned short* qrow = Qb + (size_t)(b*SEQ + qb + c) * EMB + h*HD;
        #pragma unroll
        for (int dch = 0; dch < 4; ++dch)
            qf[dch] = *(const bf16x8*)(qrow + dch*32 + g*8);
    }

    f32x4 o[8];
    #pragma unroll
    for (int ni = 0; ni < 8; ++ni) o[ni] = (f32x4){0.f, 0.f, 0.f, 0.f};
    float m4[4], l4[4];
    #pragma unroll
    for (int j = 0; j < 4; ++j) { m4[j] = -1e30f; l4[j] = 0.f; }

    const int qmaxw = qb + 15;                       // wave-uniform causal bound
    const unsigned short* Kbase = Kb  + (size_t)(b*SEQ) * EMB + h*HD;
    const unsigned short* Vbase = VTb + (size_t)((b*NH + h) * HD) * SEQ;
    const float scale = 0.08838834764831845f;        // 1/sqrt(128)
    char* pw = (char*)&p_lds[w][0];

    for (int ti = 0; ti < 8; ++ti) {
        const int tc = tc0 + ti * 64;
        if (tc > qmaxw) break;                       // wave-uniform; no barriers in loop
        // ---- QK^T: 4 key sub-tiles of 16, accumulate over d (4 mfma each)
        f32x4 sc[4];
        #pragma unroll
        for (int kt = 0; kt < 4; ++kt) {
            sc[kt] = (f32x4){0.f, 0.f, 0.f, 0.f};
            if (tc + kt*16 <= qmaxw) {               // wave-uniform skip
                const unsigned short* krow = Kbase + (size_t)(tc + kt*16 + c) * EMB;
                #pragma unroll
                for (int dch = 0; dch < 4; ++dch) {
                    bf16x8 kf = *(const bf16x8*)(krow + dch*32 + g*8);
                    sc[kt] = __builtin_amdgcn_mfma_f32_16x16x32_bf16(qf[dch], kf, sc[kt], 0, 0, 0);
                }
            }
        }
        // ---- online softmax; C layout: key col = c, q row = g*4+j
        #pragma unroll
        for (int j = 0; j < 4; ++j) {
            const int q = qb + g*4 + j;
            const int row = g*4 + j;
            float sv[4]; float mx = -1e30f;
            #pragma unroll
            for (int kt = 0; kt < 4; ++kt) {
                const int key = tc + kt*16 + c;
                sv[kt] = (key <= q) ? sc[kt][j] * scale : -1e30f;
                mx = fmaxf(mx, sv[kt]);
            }
            #pragma unroll
            for (int off = 8; off; off >>= 1) mx = fmaxf(mx, __shfl_xor(mx, off));
            const float mn = fmaxf(m4[j], mx);
            const float corr = __expf(m4[j] - mn);
            float ps = 0.f;
            #pragma unroll
            for (int kt = 0; kt < 4; ++kt) {
                const float p = __expf(sv[kt] - mn);     // masked -> 0
                ps += p;
                const int byte = (row*128 + (kt*16 + c)*2) ^ ((row & 7) << 4);
                *(unsigned short*)(pw + byte) = f2bf(p);
            }
            #pragma unroll
            for (int off = 8; off; off >>= 1) ps += __shfl_xor(ps, off);
            l4[j] = l4[j] * corr + ps;
            m4[j] = mn;
            #pragma unroll
            for (int ni = 0; ni < 8; ++ni) o[ni][j] *= corr;
        }
        asm volatile("s_waitcnt lgkmcnt(0)" ::: "memory");
        __builtin_amdgcn_sched_barrier(0);
        // ---- PV: A = P (rows q=c, t contiguous from swizzled LDS), B = VT
        #pragma unroll
        for (int kc = 0; kc < 2; ++kc) {
            if (tc + kc*32 <= qmaxw) {               // wave-uniform
                const int byte = (c*128 + kc*64 + g*16) ^ ((c & 7) << 4);
                bf16x8 pa = *(const bf16x8*)(pw + byte);
                #pragma unroll
                for (int ni = 0; ni < 8; ++ni) {
                    bf16x8 vf = *(const bf16x8*)(Vbase + (size_t)(ni*16 + c) * SEQ + tc + kc*32 + g*8);
                    o[ni] = __builtin_amdgcn_mfma_f32_16x16x32_bf16(pa, vf, o[ni], 0, 0, 0);
                }
            }
        }
    }

    // ---- epilogue: store unnormalized partial + (m, l)
    const int slot = (b*NH + h) * 80 + i;
    float* op = Opart + (size_t)slot * (64 * 128);
    #pragma unroll
    for (int ni = 0; ni < 8; ++ni)
        #pragma unroll
        for (int j = 0; j < 4; ++j)
            op[(size_t)(w*16 + g*4 + j) * 128 + ni*16 + c] = o[ni][j];
    if (c == 0) {
        #pragma unroll
        for (int j = 0; j < 4; ++j) {
            Ml[(size_t)slot * 128 +      w*16 + g*4 + j] = m4[j];
            Ml[(size_t)slot * 128 + 64 + w*16 + g*4 + j] = l4[j];
        }
    }
}

// ------------- combine KV-split partials -> bf16 ctx ------------------------
// grid (SEQ/64, NH, BATCH); thread handles one row x 32-col strip
__global__ __launch_bounds__(256) void k_attn_reduce(const float* __restrict__ Opart,
                                                     const float* __restrict__ Ml,
                                                     unsigned short* __restrict__ Ob) {
    const int qt = blockIdx.x, h = blockIdx.y, b = blockIdx.z;
    const int a = qt >> 3, r = qt & 7;
    const int slot0 = (b*NH + h) * 80 + (a + 1) * (4*a + r);
    const int nks = a + 1;
    const int row = threadIdx.x >> 2;
    const int c0 = (threadIdx.x & 3) * 32;
    float M = -1e30f;
    for (int s = 0; s < nks; ++s)
        M = fmaxf(M, Ml[(size_t)(slot0 + s) * 128 + row]);
    float L = 0.f;
    for (int s = 0; s < nks; ++s)
        L += Ml[(size_t)(slot0 + s) * 128 + 64 + row] *
             __expf(Ml[(size_t)(slot0 + s) * 128 + row] - M);
    float acc[32];
    #pragma unroll
    for (int k = 0; k < 32; ++k) acc[k] = 0.f;
    for (int s = 0; s < nks; ++s) {
        const float wi = __expf(Ml[(size_t)(slot0 + s) * 128 + row] - M);
        const float4* op = (const float4*)(Opart + ((size_t)(slot0 + s) * 64 + row) * 128 + c0);
        #pragma unroll
        for (int q4 = 0; q4 < 8; ++q4) {
            float4 v = op[q4];
            acc[q4*4+0] += v.x * wi; acc[q4*4+1] += v.y * wi;
            acc[q4*4+2] += v.z * wi; acc[q4*4+3] += v.w * wi;
        }
    }
    const float inv = 1.0f / L;
    unsigned short* orow = Ob + (size_t)(b*SEQ + qt*64 + row) * EMB + h*HD + c0;
    #pragma unroll
    for (int q4 = 0; q4 < 8; ++q4) {
        ushort4 u;
        u.x = f2bf(acc[q4*4+0] * inv); u.y = f2bf(acc[q4*4+1] * inv);
        u.z = f2bf(acc[q4*4+2] * inv); u.w = f2bf(acc[q4*4+3] * inv);
        ((ushort4*)orow)[q4] = u;
    }
}

// ---------------- row LayerNorm over 2048, optional bf16 copy ---------------
__global__ __launch_bounds__(256) void k_ln(const float* __restrict__ X,
                                            const float* __restrict__ g,
                                            const float* __restrict__ be,
                                            float* __restrict__ Of32,
                                            unsigned short* __restrict__ Obf16) {
    const int row = blockIdx.x;
    const float* x = X + (size_t)row * EMB;
    float4 v[2];
    float s = 0.f, ss = 0.f;
    #pragma unroll
    for (int i = 0; i < 2; ++i) {
        v[i] = ((const float4*)x)[threadIdx.x + i*256];
        s  += v[i].x + v[i].y + v[i].z + v[i].w;
        ss += v[i].x*v[i].x + v[i].y*v[i].y + v[i].z*v[i].z + v[i].w*v[i].w;
    }
    #pragma unroll
    for (int o = 32; o; o >>= 1) { s += __shfl_xor(s, o); ss += __shfl_xor(ss, o); }
    __shared__ float red[2][4];
    const int lane = threadIdx.x & 63, wid = threadIdx.x >> 6;
    if (lane == 0) { red[0][wid] = s; red[1][wid] = ss; }
    __syncthreads();
    s  = red[0][0] + red[0][1] + red[0][2] + red[0][3];
    ss = red[1][0] + red[1][1] + red[1][2] + red[1][3];
    const float mu = s * (1.0f / EMB);
    const float var = ss * (1.0f / EMB) - mu * mu;
    const float rs = rsqrtf(var + 1e-5f);
    #pragma unroll
    for (int i = 0; i < 2; ++i) {
        const int c4 = threadIdx.x + i*256;
        float4 gv = ((const float4*)g)[c4];
        float4 bv = ((const float4*)be)[c4];
        float4 y;
        y.x = (v[i].x - mu) * rs * gv.x + bv.x;
        y.y = (v[i].y - mu) * rs * gv.y + bv.y;
        y.z = (v[i].z - mu) * rs * gv.z + bv.z;
        y.w = (v[i].w - mu) * rs * gv.w + bv.w;
        if (Of32)  ((float4*)(Of32 + (size_t)row * EMB))[c4] = y;
        if (Obf16) {
            ushort4 u; u.x = f2bf(y.x); u.y = f2bf(y.y); u.z = f2bf(y.z); u.w = f2bf(y.w);
            ((ushort4*)(Obf16 + (size_t)row * EMB))[c4] = u;
        }
    }
}

extern "C" void kernel_launch(void* const* d_in, const int* in_sizes, int n_in,
                              void* d_out, int out_size, void* d_ws, size_t ws_size,
                              hipStream_t stream) {
    const float* emb = (const float*)d_in[0];
    const float* Wq  = (const float*)d_in[1];  const float* bq  = (const float*)d_in[2];
    const float* Wk  = (const float*)d_in[3];  const float* bk  = (const float*)d_in[4];
    const float* Wv  = (const float*)d_in[5];  const float* bv  = (const float*)d_in[6];
    const float* Wfc = (const float*)d_in[7];  const float* bfc = (const float*)d_in[8];
    const float* g1  = (const float*)d_in[9];  const float* be1 = (const float*)d_in[10];
    const float* W1  = (const float*)d_in[11]; const float* b1  = (const float*)d_in[12];
    const float* W2  = (const float*)d_in[13]; const float* b2  = (const float*)d_in[14];
    const float* g2  = (const float*)d_in[15]; const float* be2 = (const float*)d_in[16];

    // workspace layout (240 MB), lifetime-based reuse.  During attention the
    // regions of ln1B/x1f/ln1f/hB are dead -> partials overlap them.
    char* ws = (char*)d_ws;
    unsigned short* aB   = (unsigned short*)(ws + (size_t)(0  ) * (1u<<20)); // 16MB: emb bf16 -> ctx bf16
    unsigned short* ln1B = (unsigned short*)(ws + (size_t)(16 ) * (1u<<20)); // 16MB (after attn)
    float*          Ml   = (float*)         (ws + (size_t)(16 ) * (1u<<20)); // 1.25MB during attn (dead after)
    unsigned short* WtB  = (unsigned short*)(ws + (size_t)(32 ) * (1u<<20)); // 32MB transposed weight (serial reuse)
    unsigned short* Qb   = (unsigned short*)(ws + (size_t)(64 ) * (1u<<20)); // 16MB Q bf16
    unsigned short* Kb   = (unsigned short*)(ws + (size_t)(80 ) * (1u<<20)); // 16MB K bf16
    unsigned short* VTb  = (unsigned short*)(ws + (size_t)(96 ) * (1u<<20)); // 16MB V^T bf16 per head
    float*          x1f  = (float*)         (ws + (size_t)(112) * (1u<<20)); // 32MB x1 f32 (after attn)
    float*          Opart= (float*)         (ws + (size_t)(112) * (1u<<20)); // 80MB partials during attn
    float*          ln1f = (float*)         (ws + (size_t)(144) * (1u<<20)); // 32MB ln1 f32 (after attn)
    unsigned short* hB   = (unsigned short*)(ws + (size_t)(176) * (1u<<20)); // 64MB GELU(ffn1) bf16 (after attn)

    const dim3 blk(256);
    const int n4 = MTOK * EMB / 4;

    // embeddings -> bf16
    k_conv<<<dim3(n4 / 256), blk, 0, stream>>>(emb, aB, n4);

    // Q, K projections (bf16 out), V projection (per-head transposed bf16 out)
    k_transconv<<<dim3(EMB/32, EMB/32), blk, 0, stream>>>(Wq, WtB, EMB, EMB);
    k_gemm<3><<<dim3(MTOK/128, EMB/128), blk, 0, stream>>>(aB, WtB, bq, nullptr, Qb, MTOK, EMB, EMB);
    k_transconv<<<dim3(EMB/32, EMB/32), blk, 0, stream>>>(Wk, WtB, EMB, EMB);
    k_gemm<3><<<dim3(MTOK/128, EMB/128), blk, 0, stream>>>(aB, WtB, bk, nullptr, Kb, MTOK, EMB, EMB);
    k_transconv<<<dim3(EMB/32, EMB/32), blk, 0, stream>>>(Wv, WtB, EMB, EMB);
    k_gemm<4><<<dim3(MTOK/128, EMB/128), blk, 0, stream>>>(aB, WtB, bv, nullptr, VTb, MTOK, EMB, EMB);

    // KV-split MFMA flash attention -> partials -> ctx bf16 (overwrites aB)
    k_attn_part<<<dim3(80, NH, BATCH), blk, 0, stream>>>(Qb, Kb, VTb, Opart, Ml);
    k_attn_reduce<<<dim3(SEQ/64, NH, BATCH), blk, 0, stream>>>(Opart, Ml, aB);

    // x1 = ctx@Wfc + bfc + emb -> x1f
    k_transconv<<<dim3(EMB/32, EMB/32), blk, 0, stream>>>(Wfc, WtB, EMB, EMB);
    k_gemm<1><<<dim3(MTOK/128, EMB/128), blk, 0, stream>>>(aB, WtB, bfc, emb, x1f, MTOK, EMB, EMB);

    // LN1 -> f32 (ln1f) + bf16 (ln1B)
    k_ln<<<dim3(MTOK), blk, 0, stream>>>(x1f, g1, be1, ln1f, ln1B);

    // h = gelu(ln1 @ W1 + b1) -> bf16
    k_transconv<<<dim3(4*EMB/32, EMB/32), blk, 0, stream>>>(W1, WtB, EMB, 4*EMB);
    k_gemm<2><<<dim3(MTOK/128, (4*EMB)/128), blk, 0, stream>>>(ln1B, WtB, b1, nullptr, hB, MTOK, 4*EMB, EMB);

    // x2 = h @ W2 + b2 + ln1 -> d_out
    k_transconv<<<dim3(EMB/32, (4*EMB)/32), blk, 0, stream>>>(W2, WtB, 4*EMB, EMB);
    k_gemm<1><<<dim3(MTOK/128, EMB/128), blk, 0, stream>>>(hB, WtB, b2, ln1f, (float*)d_out, MTOK, EMB, 4*EMB);

    // LN2 in-place on d_out
    k_ln<<<dim3(MTOK), blk, 0, stream>>>((const float*)d_out, g2, be2, (float*)d_out, nullptr);
}